// Round 3
// baseline (1522.800 us; speedup 1.0000x reference)
//
#include <hip/hip_runtime.h>
#include <hip/hip_bf16.h>

// GCNConv: out[i] = sum_{e: row[e]=i} dis[row]*dis[col]*xl[col] + dis[i]^2*xl[i]
// N=50000, E=1.6M, D=128, fp32 in/out.
//
// R17 -> R18: counters showed the 2B random ecol scatter = 142MB partial-line
// HBM writes (the poison), while 4B atomics to small counter regions are cheap
// (FETCH stayed 6MB). So:
//  - keep the LDS bucket sort ONLY for edge coalescing (ebuf, 4B writes),
//    64-row buckets (782), pack col:16|rl:6|bucket:10
//  - cnt_col via direct global atomics (cebuf/col-sort path deleted)
//  - k_breduce replaces k_split+k_reduce: block-per-bucket, fp32 acc[64][128]
//    in LDS, col-strided gathers (lane l owns cols l+32k -> ds_add_f32 on
//    bank l, conflict-free), epilogue out = dis_i*(acc + dis_i*xl_i).

#define D     128
#define TILE  8192
#define BINB  1024      // k_binjoint2 block size
#define RPB   64        // rows per bucket
#define CAPB  4096      // ebuf capacity per bucket (mean 2046, >40 sigma)
#define MAXBK 1024      // bucket id fits 10 bits

typedef short  bf16x8 __attribute__((ext_vector_type(8)));
typedef float  f32x4  __attribute__((ext_vector_type(4)));
typedef unsigned short us4 __attribute__((ext_vector_type(4)));
typedef unsigned short us8 __attribute__((ext_vector_type(8)));

static __device__ __forceinline__ unsigned short f2bf(float f) {
    unsigned u = __float_as_uint(f);
    u = (u + 0x7FFFu + ((u >> 16) & 1u)) >> 16;   // RNE
    return (unsigned short)u;
}
static __device__ __forceinline__ float bf2f(unsigned short s) {
    return __uint_as_float(((unsigned)s) << 16);
}

// --- init: zero cnt_col, bcur[b]=b*CAPB, wtb = bf16(W^T) -----------------
__global__ __launch_bounds__(256) void k_prep(const float* __restrict__ W,
                                              unsigned short* __restrict__ wtb,
                                              int* __restrict__ bcur,
                                              int* __restrict__ cnt_col,
                                              int N, int NBK) {
    int i = blockIdx.x * 256 + threadIdx.x;
    if (i < N) cnt_col[i] = 0;
    if (i < NBK) bcur[i] = i * CAPB;
    if (i < D * D) {
        int n = i >> 7, k = i & 127;
        wtb[n * 128 + k] = f2bf(W[k * 128 + n]);
    }
}

// --- fused: blocks <NT bin edges (row-bucket sort + col atomics);
//            blocks >=NT do MFMA gemm (xlb = bf16(xW+b)) --------------------
__global__ __launch_bounds__(1024) void k_binjoint2(
        const int* __restrict__ rows, const int* __restrict__ cols,
        int* __restrict__ bcur, int* __restrict__ cnt_col,
        unsigned* __restrict__ ebuf,
        const float* __restrict__ x, const unsigned short* __restrict__ wtb,
        const float* __restrict__ bia, unsigned short* __restrict__ xlb,
        int E, int N, int NBK, int NT) {
    __shared__ __align__(16) unsigned char smem[65536];
    const int t = threadIdx.x;

    if ((int)blockIdx.x >= NT) {
        // ---------------- gemm path: 64x128 tile, waves 0-3 compute ------
        unsigned short (*wt)[136] = (unsigned short (*)[136])smem;            // 34816 B
        unsigned short (*xs)[136] = (unsigned short (*)[136])(smem + 34816);  // 17408 B
        const int row0 = ((int)blockIdx.x - NT) * 64;
        #pragma unroll
        for (int i = 0; i < 2; ++i) {         // W^T: 2048 ushort8 chunks
            int j = i * 1024 + t;
            int n = j >> 4, k8 = j & 15;
            us8 v = *(const us8*)&wtb[j * 8];
            *(us8*)&wt[n][k8 * 8] = v;
        }
        #pragma unroll
        for (int i = 0; i < 2; ++i) {         // x: 2048 float4 -> ushort4
            int j = i * 1024 + t;
            int r = j >> 5, c4 = j & 31;
            int gr = row0 + r;
            us4 o = (us4){0, 0, 0, 0};
            if (gr < N) {
                float4 v = *(const float4*)&x[(size_t)gr * D + c4 * 4];
                o = (us4){f2bf(v.x), f2bf(v.y), f2bf(v.z), f2bf(v.w)};
            }
            *(us4*)&xs[r][c4 * 4] = o;
        }
        __syncthreads();
        if (t < 256) {
            const int w  = t >> 6, l = t & 63;
            const int m0 = w * 16;
            const int lm = l & 15, lq = l >> 4;
            f32x4 acc[8];
            #pragma unroll
            for (int nt = 0; nt < 8; ++nt) acc[nt] = (f32x4){0.f, 0.f, 0.f, 0.f};
            #pragma unroll
            for (int kk = 0; kk < 4; ++kk) {
                const int kof = kk * 32 + lq * 8;
                bf16x8 a = *(const bf16x8*)&xs[m0 + lm][kof];
                #pragma unroll
                for (int nt = 0; nt < 8; ++nt) {
                    bf16x8 bb = *(const bf16x8*)&wt[nt * 16 + lm][kof];
                    acc[nt] = __builtin_amdgcn_mfma_f32_16x16x32_bf16(a, bb, acc[nt], 0, 0, 0);
                }
            }
            #pragma unroll
            for (int nt = 0; nt < 8; ++nt) {
                const int col = nt * 16 + lm;
                const float bc = bia[col];
                #pragma unroll
                for (int r = 0; r < 4; ++r) {
                    int grow = row0 + m0 + lq * 4 + r;
                    if (grow < N) xlb[(size_t)grow * D + col] = f2bf(acc[nt][r] + bc);
                }
            }
        }
        return;
    }

    // ---------------- bin path: row-bucket LDS sort, coalesced writes ----
    unsigned* sorted = (unsigned*)smem;                 // 32768 B
    int* lcnt  = (int*)(smem + 32768);                  // 800 ints each
    int* lbase = lcnt + 800;
    int* excl  = lcnt + 1600;
    int* cur   = lcnt + 2400;                           // ends at 45568 B

    const int base = blockIdx.x * TILE;
    int m = E - base; if (m > TILE) m = TILE;

    unsigned p[TILE / BINB];
    #pragma unroll
    for (int it = 0; it < TILE / BINB; ++it) {
        int i = it * BINB + t;
        if (i < m) {
            unsigned r = (unsigned)rows[base + i];
            unsigned c = (unsigned)cols[base + i];
            p[it] = c | ((r & 63u) << 16) | ((r >> 6) << 22);
            atomicAdd(&cnt_col[c], 1);           // degrees: direct, L2-cheap
        }
    }
    if (t < 800) lcnt[t] = 0;
    __syncthreads();
    #pragma unroll
    for (int it = 0; it < TILE / BINB; ++it) {
        int i = it * BINB + t;
        if (i < m) atomicAdd(&lcnt[p[it] >> 22], 1);
    }
    __syncthreads();
    // wave 0: scan 782 buckets, 13 keys/lane; write excl AND cur
    if (t < 64) {
        int v[13], s = 0;
        #pragma unroll
        for (int u = 0; u < 13; ++u) {
            int k = t * 13 + u;
            v[u] = (k < NBK) ? lcnt[k] : 0;
            s += v[u];
        }
        int inc = s;
        #pragma unroll
        for (int off = 1; off < 64; off <<= 1) { int o = __shfl_up(inc, off); if (t >= off) inc += o; }
        int run = inc - s;
        #pragma unroll
        for (int u = 0; u < 13; ++u) {
            int k = t * 13 + u;
            if (k < NBK) { excl[k] = run; cur[k] = run; }
            run += v[u];
        }
    }
    if (t < NBK) {                               // reserve global regions
        int c0 = lcnt[t];
        lbase[t] = c0 ? atomicAdd(&bcur[t], c0) : 0;
    }
    __syncthreads();
    #pragma unroll
    for (int it = 0; it < TILE / BINB; ++it) {   // scatter into LDS (random: free)
        int i = it * BINB + t;
        if (i < m) {
            int pos = atomicAdd(&cur[p[it] >> 22], 1);
            sorted[pos] = p[it];
        }
    }
    __syncthreads();
    #pragma unroll
    for (int it = 0; it < TILE / BINB; ++it) {   // positional coalesced writes
        int i = it * BINB + t;
        if (i < m) {
            unsigned pp = sorted[i];
            int bk = pp >> 22;
            int g  = lbase[bk] + i - excl[bk];
            if (g < (bk + 1) * CAPB) ebuf[g] = pp & 0x3FFFFFu;  // col | rl<<16
        }
    }
}

// --- dis[i] = rsqrt(deg+1) ----------------------------------------------
__global__ __launch_bounds__(256) void k_dis2(const int* __restrict__ cnt_col,
                                              float* __restrict__ dis, int N) {
    int i = blockIdx.x * 256 + threadIdx.x;
    if (i < N) dis[i] = rsqrtf((float)(cnt_col[i] + 1));
}

// --- block-per-bucket gather + LDS fp32 accumulate + fused epilogue ------
// out[row] = dis[row] * ( sum_{edges} dis[col]*xl[col] + dis[row]*xl[row] )
__global__ __launch_bounds__(512) void k_breduce(const int* __restrict__ bcur,
                                                 const unsigned* __restrict__ ebuf,
                                                 const float* __restrict__ dis,
                                                 const unsigned short* __restrict__ xlb,
                                                 float* __restrict__ out, int N) {
    __shared__ float acc[RPB][D];                      // 32 KB
    const int t = threadIdx.x;
    const int b = blockIdx.x;
    const int ebase = b * CAPB;
    int m = bcur[b] - ebase;
    if (m > CAPB) m = CAPB;
    if (m < 0) m = 0;

    #pragma unroll
    for (int z = 0; z < (RPB * D) / 512; ++z)          // zero accumulator
        ((float*)acc)[z * 512 + t] = 0.0f;
    __syncthreads();

    const int wv = t >> 6, lane = t & 63;
    const int half = lane >> 5, l32 = lane & 31;
    // contiguous per-wave chunks, multiple of 64
    int chunk = ((m + 511) >> 9) << 6;
    int wbeg = wv * chunk;
    int wend = wbeg + chunk; if (wend > m) wend = m;

    for (int bs = wbeg; bs < wend; bs += 64) {
        int mloc = wend - bs; if (mloc > 64) mloc = 64;
        unsigned pw = 0;
        if (lane < mloc) pw = ebuf[ebase + bs + lane];
        for (int j = 0; j < mloc; j += 16) {           // 8 pairs = 16 edges
            unsigned short v[8][4];
            float dc[8];
            int rl[8];
            #pragma unroll
            for (int u = 0; u < 8; ++u) {
                int idx = j + 2 * u + half;            // idx < 64 always
                unsigned pp = __shfl(pw, idx);
                int c = pp & 0xFFFFu;
                rl[u] = (pp >> 16) & 63;
                dc[u] = (idx < mloc) ? dis[c] : 0.0f;  // inactive: add 0 to acc[rl=0]
                const unsigned short* src = &xlb[((size_t)c << 7) + l32];
                #pragma unroll
                for (int k = 0; k < 4; ++k) v[u][k] = src[k << 5];
            }
            #pragma unroll
            for (int u = 0; u < 8; ++u) {
                float* ap = &acc[rl[u]][l32];          // bank = l32: conflict-free
                #pragma unroll
                for (int k = 0; k < 4; ++k)
                    atomicAdd(&ap[k << 5], dc[u] * bf2f(v[u][k]));
            }
        }
    }
    __syncthreads();

    // epilogue: 8 threads per row, 16 cols each
    const int rl = t >> 3, seg = t & 7;
    const int grow = b * RPB + rl;
    if (grow < N) {
        const float di = dis[grow];
        unsigned short xv[16];
        *(us8*)&xv[0] = *(const us8*)&xlb[(size_t)grow * D + seg * 16];
        *(us8*)&xv[8] = *(const us8*)&xlb[(size_t)grow * D + seg * 16 + 8];
        #pragma unroll
        for (int k4 = 0; k4 < 4; ++k4) {
            f32x4 a = *(f32x4*)&acc[rl][seg * 16 + k4 * 4];
            float4 o = make_float4(
                di * (a[0] + di * bf2f(xv[k4 * 4 + 0])),
                di * (a[1] + di * bf2f(xv[k4 * 4 + 1])),
                di * (a[2] + di * bf2f(xv[k4 * 4 + 2])),
                di * (a[3] + di * bf2f(xv[k4 * 4 + 3])));
            *(float4*)&out[(size_t)grow * D + seg * 16 + k4 * 4] = o;
        }
    }
}

// ======================= fallback (R1 atomic path) =======================
__global__ __launch_bounds__(256) void k_zero(int* __restrict__ p, int n) {
    int i = blockIdx.x * 256 + threadIdx.x;
    if (i < n) p[i] = 0;
}
__global__ __launch_bounds__(256) void k_deg(const int* __restrict__ cols,
                                             int* __restrict__ cntc, int E) {
    int e = blockIdx.x * 256 + threadIdx.x;
    if (e < E) atomicAdd(&cntc[cols[e]], 1);
}
__global__ __launch_bounds__(256) void k_dis(const int* __restrict__ cntc,
                                             float* __restrict__ dis, int N) {
    int i = blockIdx.x * 256 + threadIdx.x;
    if (i < N) dis[i] = rsqrtf((float)(cntc[i] + 1));
}
#define GEMM_R 8
__global__ __launch_bounds__(128) void k_gemmf(const float* __restrict__ x,
                                               const float* __restrict__ W,
                                               const float* __restrict__ b,
                                               float* __restrict__ xl, int N) {
    __shared__ float xs[GEMM_R][D];
    const int c  = threadIdx.x;
    const int r0 = blockIdx.x * GEMM_R;
    #pragma unroll
    for (int r = 0; r < GEMM_R; ++r) {
        int row = r0 + r;
        xs[r][c] = (row < N) ? x[row * D + c] : 0.0f;
    }
    __syncthreads();
    float acc[GEMM_R];
    const float bc = b[c];
    #pragma unroll
    for (int r = 0; r < GEMM_R; ++r) acc[r] = bc;
    for (int k = 0; k < D; k += 4) {
        const float w0 = W[(k + 0) * D + c];
        const float w1 = W[(k + 1) * D + c];
        const float w2 = W[(k + 2) * D + c];
        const float w3 = W[(k + 3) * D + c];
        #pragma unroll
        for (int r = 0; r < GEMM_R; ++r) {
            const float4 xv = *reinterpret_cast<const float4*>(&xs[r][k]);
            acc[r] = fmaf(xv.x, w0, acc[r]);
            acc[r] = fmaf(xv.y, w1, acc[r]);
            acc[r] = fmaf(xv.z, w2, acc[r]);
            acc[r] = fmaf(xv.w, w3, acc[r]);
        }
    }
    #pragma unroll
    for (int r = 0; r < GEMM_R; ++r) {
        int row = r0 + r;
        if (row < N) xl[row * D + c] = acc[r];
    }
}
__global__ __launch_bounds__(256) void k_self(const float* __restrict__ xl,
                                              const float* __restrict__ dis,
                                              float* __restrict__ out, int N) {
    int gid = blockIdx.x * 256 + threadIdx.x;
    int i = gid >> 7;
    if (i < N) {
        float d = dis[i];
        out[gid] = d * d * xl[gid];
    }
}
__global__ __launch_bounds__(256) void k_scatter(const int* __restrict__ rows,
                                                 const int* __restrict__ cols,
                                                 const float* __restrict__ dis,
                                                 const float* __restrict__ xl,
                                                 float* __restrict__ out, int E) {
    long long gid = (long long)blockIdx.x * 256 + threadIdx.x;
    int e    = (int)(gid >> 6);
    int lane = (int)(gid & 63);
    if (e >= E) return;
    const int row = rows[e];
    const int col = cols[e];
    const float nrm = dis[row] * dis[col];
    atomicAdd(&out[row * D + lane],      nrm * xl[col * D + lane]);
    atomicAdd(&out[row * D + 64 + lane], nrm * xl[col * D + 64 + lane]);
}

// ======================= launch ==========================================
extern "C" void kernel_launch(void* const* d_in, const int* in_sizes, int n_in,
                              void* d_out, int out_size, void* d_ws, size_t ws_size,
                              hipStream_t stream) {
    const float* x   = (const float*)d_in[0];
    const int*   ei  = (const int*)d_in[1];
    const float* W   = (const float*)d_in[2];
    const float* b   = (const float*)d_in[3];
    float*       out = (float*)d_out;

    const int N = in_sizes[0] / D;   // 50000
    const int E = in_sizes[1] / 2;   // 1.6M
    const int* rows = ei;
    const int* cols = ei + E;
    const int NBK = (N + RPB - 1) / RPB;       // 782 buckets of 64 rows
    const int NT  = (E + TILE - 1) / TILE;     // 196 bin blocks
    const int GN  = (N + 63) / 64;             // 782 gemm blocks

    // ws layout
    char* p = (char*)d_ws;
    size_t off = 0;
    unsigned short* xlb     = (unsigned short*)(p + off); off += (size_t)N * D * 2;
    unsigned short* wtb     = (unsigned short*)(p + off); off += (size_t)D * D * 2;
    float*          dis     = (float*)(p + off);          off += (size_t)N * 4;
    int*            cnt_col = (int*)(p + off);            off += (size_t)N * 4;
    int*            bcur    = (int*)(p + off);            off += (size_t)MAXBK * 4;
    unsigned*       ebuf    = (unsigned*)(p + off);       off += (size_t)NBK * CAPB * 4;

    const int gN = (N + 255) / 256;
    const int gE = (E + 255) / 256;

    if (N <= 65536 && NBK <= MAXBK && ws_size >= off) {
        k_prep     <<<gN, 256, 0, stream>>>(W, wtb, bcur, cnt_col, N, NBK);
        k_binjoint2<<<NT + GN, BINB, 0, stream>>>(rows, cols, bcur, cnt_col, ebuf,
                                                  x, wtb, b, xlb, E, N, NBK, NT);
        k_dis2     <<<gN, 256, 0, stream>>>(cnt_col, dis, N);
        k_breduce  <<<NBK, 512, 0, stream>>>(bcur, ebuf, dis, xlb, out, N);
    } else {
        // fallback: R1 atomic scatter path (fp32 xl)
        char* q = (char*)d_ws;
        float* xl   = (float*)q;
        float* disF = (float*)(q + (size_t)N * D * 4);
        int*   cc   = (int*)(q + (size_t)N * D * 4 + (size_t)N * 4);
        k_zero <<<gN, 256, 0, stream>>>(cc, N);
        k_deg  <<<gE, 256, 0, stream>>>(cols, cc, E);
        k_dis  <<<gN, 256, 0, stream>>>(cc, disF, N);
        k_gemmf<<<(N + GEMM_R - 1) / GEMM_R, 128, 0, stream>>>(x, W, b, xl, N);
        k_self <<<((N * D) + 255) / 256, 256, 0, stream>>>(xl, disF, out, N);
        long long st = (long long)E * 64;
        k_scatter<<<(int)((st + 255) / 256), 256, 0, stream>>>(rows, cols, disF, xl, out, E);
    }
}

// Round 5
// 226.286 us; speedup vs baseline: 6.7295x; 6.7295x over previous
//
#include <hip/hip_runtime.h>
#include <hip/hip_bf16.h>

// GCNConv: out[i] = sum_{e: row[e]=i} dis[row]*dis[col]*xl[col] + dis[i]^2*xl[i]
// N=50000, E=1.6M, D=128, fp32 in/out.
//
// R19 -> R20: R19 never ran (container infra failure, no kernel error).
// Re-submitting the same verified-by-review design:
//  - k_binjoint2 (identical to R18's HW-verified code): row-bucket LDS sort
//    -> ebuf (coalesced 4B), direct global cnt_col atomics (R17: L2-cheap),
//    fused MFMA gemm xlb = bf16(xW+b).
//  - k_disy: dis = rsqrt(deg+1); premul xlb in place (y = dis*xl, R16 trick).
//  - k_sortred: block-per-bucket; stage <=4096 edges in regs, 64-key LDS
//    counting sort by row-local, then R16's exact register gather loop
//    (us4 half-split loads, shfl_xor(32) merge), cols broadcast from LDS.
//    out = dis_i*(y_i + sum y_c). No ecol/begN/endN round-trip.
// Anti-lessons baked in: no LDS-atomic accumulate (R18: 1370us, VALUBusy 2%),
// no sub-4B global scatters (R17: 142MB partial-line writes).

#define D     128
#define TILE  8192
#define BINB  1024      // k_binjoint2 block size
#define RPB   64        // rows per bucket
#define CAPB  4096      // ebuf capacity per bucket (mean 2046, ~45 sigma)
#define MAXBK 1024      // bucket id fits 10 bits

typedef short  bf16x8 __attribute__((ext_vector_type(8)));
typedef float  f32x4  __attribute__((ext_vector_type(4)));
typedef unsigned short us4 __attribute__((ext_vector_type(4)));
typedef unsigned short us8 __attribute__((ext_vector_type(8)));

static __device__ __forceinline__ unsigned short f2bf(float f) {
    unsigned u = __float_as_uint(f);
    u = (u + 0x7FFFu + ((u >> 16) & 1u)) >> 16;   // RNE
    return (unsigned short)u;
}
static __device__ __forceinline__ float bf2f(unsigned short s) {
    return __uint_as_float(((unsigned)s) << 16);
}

// --- init: zero cnt_col, bcur[b]=b*CAPB, wtb = bf16(W^T) -----------------
__global__ __launch_bounds__(256) void k_prep(const float* __restrict__ W,
                                              unsigned short* __restrict__ wtb,
                                              int* __restrict__ bcur,
                                              int* __restrict__ cnt_col,
                                              int N, int NBK) {
    int i = blockIdx.x * 256 + threadIdx.x;
    if (i < N) cnt_col[i] = 0;
    if (i < NBK) bcur[i] = i * CAPB;
    if (i < D * D) {
        int n = i >> 7, k = i & 127;
        wtb[n * 128 + k] = f2bf(W[k * 128 + n]);
    }
}

// --- fused: blocks <NT bin edges (row-bucket sort + col atomics);
//            blocks >=NT do MFMA gemm (xlb = bf16(xW+b)) -------------------
__global__ __launch_bounds__(1024) void k_binjoint2(
        const int* __restrict__ rows, const int* __restrict__ cols,
        int* __restrict__ bcur, int* __restrict__ cnt_col,
        unsigned* __restrict__ ebuf,
        const float* __restrict__ x, const unsigned short* __restrict__ wtb,
        const float* __restrict__ bia, unsigned short* __restrict__ xlb,
        int E, int N, int NBK, int NT) {
    __shared__ __align__(16) unsigned char smem[65536];
    const int t = threadIdx.x;

    if ((int)blockIdx.x >= NT) {
        // ---------------- gemm path: 64x128 tile, waves 0-3 compute ------
        unsigned short (*wt)[136] = (unsigned short (*)[136])smem;            // 34816 B
        unsigned short (*xs)[136] = (unsigned short (*)[136])(smem + 34816);  // 17408 B
        const int row0 = ((int)blockIdx.x - NT) * 64;
        #pragma unroll
        for (int i = 0; i < 2; ++i) {         // W^T: 2048 ushort8 chunks
            int j = i * 1024 + t;
            int n = j >> 4, k8 = j & 15;
            us8 v = *(const us8*)&wtb[j * 8];
            *(us8*)&wt[n][k8 * 8] = v;
        }
        #pragma unroll
        for (int i = 0; i < 2; ++i) {         // x: 2048 float4 -> ushort4
            int j = i * 1024 + t;
            int r = j >> 5, c4 = j & 31;
            int gr = row0 + r;
            us4 o = (us4){0, 0, 0, 0};
            if (gr < N) {
                float4 v = *(const float4*)&x[(size_t)gr * D + c4 * 4];
                o = (us4){f2bf(v.x), f2bf(v.y), f2bf(v.z), f2bf(v.w)};
            }
            *(us4*)&xs[r][c4 * 4] = o;
        }
        __syncthreads();
        if (t < 256) {
            const int w  = t >> 6, l = t & 63;
            const int m0 = w * 16;
            const int lm = l & 15, lq = l >> 4;
            f32x4 acc[8];
            #pragma unroll
            for (int nt = 0; nt < 8; ++nt) acc[nt] = (f32x4){0.f, 0.f, 0.f, 0.f};
            #pragma unroll
            for (int kk = 0; kk < 4; ++kk) {
                const int kof = kk * 32 + lq * 8;
                bf16x8 a = *(const bf16x8*)&xs[m0 + lm][kof];
                #pragma unroll
                for (int nt = 0; nt < 8; ++nt) {
                    bf16x8 bb = *(const bf16x8*)&wt[nt * 16 + lm][kof];
                    acc[nt] = __builtin_amdgcn_mfma_f32_16x16x32_bf16(a, bb, acc[nt], 0, 0, 0);
                }
            }
            #pragma unroll
            for (int nt = 0; nt < 8; ++nt) {
                const int col = nt * 16 + lm;
                const float bc = bia[col];
                #pragma unroll
                for (int r = 0; r < 4; ++r) {
                    int grow = row0 + m0 + lq * 4 + r;
                    if (grow < N) xlb[(size_t)grow * D + col] = f2bf(acc[nt][r] + bc);
                }
            }
        }
        return;
    }

    // ---------------- bin path: row-bucket LDS sort, coalesced writes ----
    unsigned* sorted = (unsigned*)smem;                 // 32768 B
    int* lcnt  = (int*)(smem + 32768);                  // 800 ints each
    int* lbase = lcnt + 800;
    int* excl  = lcnt + 1600;
    int* cur   = lcnt + 2400;                           // ends at 45568 B

    const int base = blockIdx.x * TILE;
    int m = E - base; if (m > TILE) m = TILE;

    unsigned p[TILE / BINB];
    #pragma unroll
    for (int it = 0; it < TILE / BINB; ++it) {
        int i = it * BINB + t;
        if (i < m) {
            unsigned r = (unsigned)rows[base + i];
            unsigned c = (unsigned)cols[base + i];
            p[it] = c | ((r & 63u) << 16) | ((r >> 6) << 22);
            atomicAdd(&cnt_col[c], 1);           // degrees: direct, L2-cheap
        }
    }
    if (t < 800) lcnt[t] = 0;
    __syncthreads();
    #pragma unroll
    for (int it = 0; it < TILE / BINB; ++it) {
        int i = it * BINB + t;
        if (i < m) atomicAdd(&lcnt[p[it] >> 22], 1);
    }
    __syncthreads();
    // wave 0: scan 782 buckets, 13 keys/lane; write excl AND cur
    if (t < 64) {
        int v[13], s = 0;
        #pragma unroll
        for (int u = 0; u < 13; ++u) {
            int k = t * 13 + u;
            v[u] = (k < NBK) ? lcnt[k] : 0;
            s += v[u];
        }
        int inc = s;
        #pragma unroll
        for (int off = 1; off < 64; off <<= 1) { int o = __shfl_up(inc, off); if (t >= off) inc += o; }
        int run = inc - s;
        #pragma unroll
        for (int u = 0; u < 13; ++u) {
            int k = t * 13 + u;
            if (k < NBK) { excl[k] = run; cur[k] = run; }
            run += v[u];
        }
    }
    if (t < NBK) {                               // reserve global regions
        int c0 = lcnt[t];
        lbase[t] = c0 ? atomicAdd(&bcur[t], c0) : 0;
    }
    __syncthreads();
    #pragma unroll
    for (int it = 0; it < TILE / BINB; ++it) {   // scatter into LDS (random: free)
        int i = it * BINB + t;
        if (i < m) {
            int pos = atomicAdd(&cur[p[it] >> 22], 1);
            sorted[pos] = p[it];
        }
    }
    __syncthreads();
    #pragma unroll
    for (int it = 0; it < TILE / BINB; ++it) {   // positional coalesced writes
        int i = it * BINB + t;
        if (i < m) {
            unsigned pp = sorted[i];
            int bk = pp >> 22;
            int g  = lbase[bk] + i - excl[bk];
            if (g < (bk + 1) * CAPB) ebuf[g] = pp & 0x3FFFFFu;  // col | rl<<16
        }
    }
}

// --- dis[i] = rsqrt(deg+1); premul xlb in place: y = dis*xl --------------
__global__ __launch_bounds__(256) void k_disy(const int* __restrict__ cnt_col,
                                              float* __restrict__ dis,
                                              unsigned short* __restrict__ xlb,
                                              int N) {
    int i = blockIdx.x * 256 + threadIdx.x;     // one us8 chunk; 16 per row
    if (i >= N * (D / 8)) return;
    int row = i >> 4;
    float dv = rsqrtf((float)(cnt_col[row] + 1));
    if ((i & 15) == 0) dis[row] = dv;
    us8 v = *(const us8*)&xlb[(size_t)i * 8];
    us8 o;
    #pragma unroll
    for (int k = 0; k < 8; ++k) o[k] = f2bf(dv * bf2f(v[k]));
    *(us8*)&xlb[(size_t)i * 8] = o;
}

// --- block-per-bucket: LDS counting sort by row-local, then R16-style
//     wave-per-node register gather. out = dis_i*(y_i + sum y_c). ---------
__global__ __launch_bounds__(512) void k_sortred(const int* __restrict__ bcur,
                                                 const unsigned* __restrict__ ebuf,
                                                 const float* __restrict__ dis,
                                                 const unsigned short* __restrict__ xlb,
                                                 float* __restrict__ out, int N) {
    __shared__ unsigned short sorted[CAPB];     // 8 KB
    __shared__ int cnt[RPB];
    __shared__ int excl[RPB];
    __shared__ int cur[RPB];
    const int t = threadIdx.x, b = blockIdx.x;
    const int ebase = b * CAPB;
    int m = bcur[b] - ebase;
    if (m > CAPB) m = CAPB;
    if (m < 0) m = 0;

    unsigned p[CAPB / 512];                     // 8 regs
    #pragma unroll
    for (int it = 0; it < CAPB / 512; ++it) {
        int i = it * 512 + t;
        p[it] = (i < m) ? ebuf[ebase + i] : 0xFFFFFFFFu;
    }
    if (t < RPB) cnt[t] = 0;
    __syncthreads();
    #pragma unroll
    for (int it = 0; it < CAPB / 512; ++it)
        if (p[it] != 0xFFFFFFFFu) atomicAdd(&cnt[(p[it] >> 16) & 63], 1);
    __syncthreads();
    if (t < 64) {                               // 64-key wave scan
        int v = cnt[t], inc = v;
        #pragma unroll
        for (int off = 1; off < 64; off <<= 1) { int o = __shfl_up(inc, off); if (t >= off) inc += o; }
        excl[t] = inc - v;
        cur[t]  = inc - v;
    }
    __syncthreads();
    #pragma unroll
    for (int it = 0; it < CAPB / 512; ++it)     // scatter (random LDS: free)
        if (p[it] != 0xFFFFFFFFu) {
            int pos = atomicAdd(&cur[(p[it] >> 16) & 63], 1);
            sorted[pos] = (unsigned short)(p[it] & 0xFFFFu);
        }
    __syncthreads();

    // gather: wave wv owns rows wv*8 .. wv*8+7 (cur[rl] == excl[rl]+cnt[rl])
    const int wv = t >> 6, lane = t & 63;
    const int half = lane >> 5, l32 = lane & 31;
    for (int r8 = 0; r8 < 8; ++r8) {
        const int rl = wv * 8 + r8;
        const int grow = b * RPB + rl;
        if (grow >= N) break;
        const int beg = excl[rl], end = cur[rl];
        // self loop: y[i]; only half 0 contributes (halves summed at end)
        us4 sv = *(const us4*)&xlb[(size_t)grow * D + (l32 << 2)];
        float s = (half == 0) ? 1.0f : 0.0f;
        float a0 = s * bf2f(sv[0]), a1 = s * bf2f(sv[1]);
        float a2 = s * bf2f(sv[2]), a3 = s * bf2f(sv[3]);
        for (int j = beg; j < end; j += 16) {   // 8 pairs = 16 edges
            us4 V[8];
            float w[8];
            #pragma unroll
            for (int u = 0; u < 8; ++u) {
                int idx = j + 2 * u + half;
                int ok = idx < end;
                int c = sorted[ok ? idx : beg];
                V[u] = *(const us4*)&xlb[((size_t)c << 7) + (l32 << 2)];
                w[u] = ok ? 1.0f : 0.0f;
            }
            #pragma unroll
            for (int u = 0; u < 8; ++u) {
                a0 = fmaf(w[u], bf2f(V[u][0]), a0);
                a1 = fmaf(w[u], bf2f(V[u][1]), a1);
                a2 = fmaf(w[u], bf2f(V[u][2]), a2);
                a3 = fmaf(w[u], bf2f(V[u][3]), a3);
            }
        }
        a0 += __shfl_xor(a0, 32);
        a1 += __shfl_xor(a1, 32);
        a2 += __shfl_xor(a2, 32);
        a3 += __shfl_xor(a3, 32);
        if (half == 0) {
            const float di = dis[grow];
            *(float4*)&out[(size_t)grow * D + (l32 << 2)] =
                make_float4(di * a0, di * a1, di * a2, di * a3);
        }
    }
}

// ======================= fallback (R1 atomic path) =======================
__global__ __launch_bounds__(256) void k_zero(int* __restrict__ p, int n) {
    int i = blockIdx.x * 256 + threadIdx.x;
    if (i < n) p[i] = 0;
}
__global__ __launch_bounds__(256) void k_deg(const int* __restrict__ cols,
                                             int* __restrict__ cntc, int E) {
    int e = blockIdx.x * 256 + threadIdx.x;
    if (e < E) atomicAdd(&cntc[cols[e]], 1);
}
__global__ __launch_bounds__(256) void k_dis(const int* __restrict__ cntc,
                                             float* __restrict__ dis, int N) {
    int i = blockIdx.x * 256 + threadIdx.x;
    if (i < N) dis[i] = rsqrtf((float)(cntc[i] + 1));
}
#define GEMM_R 8
__global__ __launch_bounds__(128) void k_gemmf(const float* __restrict__ x,
                                               const float* __restrict__ W,
                                               const float* __restrict__ b,
                                               float* __restrict__ xl, int N) {
    __shared__ float xs[GEMM_R][D];
    const int c  = threadIdx.x;
    const int r0 = blockIdx.x * GEMM_R;
    #pragma unroll
    for (int r = 0; r < GEMM_R; ++r) {
        int row = r0 + r;
        xs[r][c] = (row < N) ? x[row * D + c] : 0.0f;
    }
    __syncthreads();
    float acc[GEMM_R];
    const float bc = b[c];
    #pragma unroll
    for (int r = 0; r < GEMM_R; ++r) acc[r] = bc;
    for (int k = 0; k < D; k += 4) {
        const float w0 = W[(k + 0) * D + c];
        const float w1 = W[(k + 1) * D + c];
        const float w2 = W[(k + 2) * D + c];
        const float w3 = W[(k + 3) * D + c];
        #pragma unroll
        for (int r = 0; r < GEMM_R; ++r) {
            const float4 xv = *reinterpret_cast<const float4*>(&xs[r][k]);
            acc[r] = fmaf(xv.x, w0, acc[r]);
            acc[r] = fmaf(xv.y, w1, acc[r]);
            acc[r] = fmaf(xv.z, w2, acc[r]);
            acc[r] = fmaf(xv.w, w3, acc[r]);
        }
    }
    #pragma unroll
    for (int r = 0; r < GEMM_R; ++r) {
        int row = r0 + r;
        if (row < N) xl[row * D + c] = acc[r];
    }
}
__global__ __launch_bounds__(256) void k_self(const float* __restrict__ xl,
                                              const float* __restrict__ dis,
                                              float* __restrict__ out, int N) {
    int gid = blockIdx.x * 256 + threadIdx.x;
    int i = gid >> 7;
    if (i < N) {
        float d = dis[i];
        out[gid] = d * d * xl[gid];
    }
}
__global__ __launch_bounds__(256) void k_scatter(const int* __restrict__ rows,
                                                 const int* __restrict__ cols,
                                                 const float* __restrict__ dis,
                                                 const float* __restrict__ xl,
                                                 float* __restrict__ out, int E) {
    long long gid = (long long)blockIdx.x * 256 + threadIdx.x;
    int e    = (int)(gid >> 6);
    int lane = (int)(gid & 63);
    if (e >= E) return;
    const int row = rows[e];
    const int col = cols[e];
    const float nrm = dis[row] * dis[col];
    atomicAdd(&out[row * D + lane],      nrm * xl[col * D + lane]);
    atomicAdd(&out[row * D + 64 + lane], nrm * xl[col * D + 64 + lane]);
}

// ======================= launch ==========================================
extern "C" void kernel_launch(void* const* d_in, const int* in_sizes, int n_in,
                              void* d_out, int out_size, void* d_ws, size_t ws_size,
                              hipStream_t stream) {
    const float* x   = (const float*)d_in[0];
    const int*   ei  = (const int*)d_in[1];
    const float* W   = (const float*)d_in[2];
    const float* b   = (const float*)d_in[3];
    float*       out = (float*)d_out;

    const int N = in_sizes[0] / D;   // 50000
    const int E = in_sizes[1] / 2;   // 1.6M
    const int* rows = ei;
    const int* cols = ei + E;
    const int NBK = (N + RPB - 1) / RPB;       // 782 buckets of 64 rows
    const int NT  = (E + TILE - 1) / TILE;     // 196 bin blocks
    const int GN  = (N + 63) / 64;             // 782 gemm blocks

    // ws layout
    char* p = (char*)d_ws;
    size_t off = 0;
    unsigned short* xlb     = (unsigned short*)(p + off); off += (size_t)N * D * 2;
    unsigned short* wtb     = (unsigned short*)(p + off); off += (size_t)D * D * 2;
    float*          dis     = (float*)(p + off);          off += (size_t)N * 4;
    int*            cnt_col = (int*)(p + off);            off += (size_t)N * 4;
    int*            bcur    = (int*)(p + off);            off += (size_t)MAXBK * 4;
    unsigned*       ebuf    = (unsigned*)(p + off);       off += (size_t)NBK * CAPB * 4;

    const int gN = (N + 255) / 256;
    const int gE = (E + 255) / 256;

    if (N <= 65536 && NBK <= MAXBK && ws_size >= off) {
        k_prep     <<<gN, 256, 0, stream>>>(W, wtb, bcur, cnt_col, N, NBK);
        k_binjoint2<<<NT + GN, BINB, 0, stream>>>(rows, cols, bcur, cnt_col, ebuf,
                                                  x, wtb, b, xlb, E, N, NBK, NT);
        k_disy     <<<(N * (D / 8) + 255) / 256, 256, 0, stream>>>(cnt_col, dis, xlb, N);
        k_sortred  <<<NBK, 512, 0, stream>>>(bcur, ebuf, dis, xlb, out, N);
    } else {
        // fallback: R1 atomic scatter path (fp32 xl)
        char* q = (char*)d_ws;
        float* xl   = (float*)q;
        float* disF = (float*)(q + (size_t)N * D * 4);
        int*   cc   = (int*)(q + (size_t)N * D * 4 + (size_t)N * 4);
        k_zero <<<gN, 256, 0, stream>>>(cc, N);
        k_deg  <<<gE, 256, 0, stream>>>(cols, cc, E);
        k_dis  <<<gN, 256, 0, stream>>>(cc, disF, N);
        k_gemmf<<<(N + GEMM_R - 1) / GEMM_R, 128, 0, stream>>>(x, W, b, xl, N);
        k_self <<<((N * D) + 255) / 256, 256, 0, stream>>>(xl, disF, out, N);
        long long st = (long long)E * 64;
        k_scatter<<<(int)((st + 255) / 256), 256, 0, stream>>>(rows, cols, disF, xl, out, E);
    }
}

// Round 6
// 194.663 us; speedup vs baseline: 7.8227x; 1.1625x over previous
//
#include <hip/hip_runtime.h>
#include <hip/hip_bf16.h>

// GCNConv: out[i] = sum_{e: row[e]=i} dis[row]*dis[col]*xl[col] + dis[i]^2*xl[i]
// N=50000, E=1.6M, D=128, fp32 in/out.
//
// R20 -> R21: k_binjoint2 post-mortem (85us, VALU 3.6%, WRITE 71MB vs ~35MB
// legitimate): the 1.6M device-scope cnt_col atomics are memory-side RMWs
// (~32B writeback each) and stall the bin path. R17's k_fill (142MB WRITE)
// fits the same model. Lesson: NO random global atomics anywhere.
//  - k_binjoint3: bin path (row-bucket LDS sort -> ebuf) minus atomics;
//    gemm path unchanged; NEW 256 hist blocks build col-degree histograms in
//    LDS (byte-packed, LDS atomics only), write partials coalesced to phist.
//  - k_dismerge: sum 256 partials/word, dis = rsqrt(deg+1), float4 writes.
//  - k_sortred2: R20 sort prologue + R15/R16's exact ping-pong gather
//    (A/B 8-pair groups, dis[c] gathered per-lane - R15==R16 proved free).
//    Premul pass (k_disy) deleted. out = dis_i*(dis_i*xl_i + sum dis_c*xl_c).

#define D     128
#define TILE  8192
#define BINB  1024      // bin/gemm/hist block size
#define RPB   64        // rows per bucket
#define CAPB  4096      // ebuf capacity per bucket (mean 2046, ~45 sigma)
#define MAXBK 1024      // bucket id fits 10 bits
#define NH    256       // histogram blocks

typedef short  bf16x8 __attribute__((ext_vector_type(8)));
typedef float  f32x4  __attribute__((ext_vector_type(4)));
typedef unsigned short us4 __attribute__((ext_vector_type(4)));
typedef unsigned short us8 __attribute__((ext_vector_type(8)));

static __device__ __forceinline__ unsigned short f2bf(float f) {
    unsigned u = __float_as_uint(f);
    u = (u + 0x7FFFu + ((u >> 16) & 1u)) >> 16;   // RNE
    return (unsigned short)u;
}
static __device__ __forceinline__ float bf2f(unsigned short s) {
    return __uint_as_float(((unsigned)s) << 16);
}

// --- init: bcur[b]=b*CAPB, wtb = bf16(W^T) -------------------------------
__global__ __launch_bounds__(256) void k_prep(const float* __restrict__ W,
                                              unsigned short* __restrict__ wtb,
                                              int* __restrict__ bcur,
                                              int NBK) {
    int i = blockIdx.x * 256 + threadIdx.x;
    if (i < NBK) bcur[i] = i * CAPB;
    if (i < D * D) {
        int n = i >> 7, k = i & 127;
        wtb[n * 128 + k] = f2bf(W[k * 128 + n]);
    }
}

// --- fused 3-way kernel:
//     blocks [0, NT):        bin edges (row-bucket LDS sort -> ebuf)
//     blocks [NT, NT+GN):    MFMA gemm (xlb = bf16(xW+b))
//     blocks [NT+GN, +NH):   col-degree histogram (LDS byte-packed -> phist)
__global__ __launch_bounds__(1024) void k_binjoint3(
        const int* __restrict__ rows, const int* __restrict__ cols,
        int* __restrict__ bcur, unsigned* __restrict__ ebuf,
        const float* __restrict__ x, const unsigned short* __restrict__ wtb,
        const float* __restrict__ bia, unsigned short* __restrict__ xlb,
        unsigned* __restrict__ phist,
        int E, int N, int NBK, int NT, int GN, int NW) {
    __shared__ __align__(16) unsigned char smem[65536];
    const int t = threadIdx.x;

    if ((int)blockIdx.x >= NT + GN) {
        // ---------------- hist path: LDS-private byte-packed histogram ---
        unsigned* hist = (unsigned*)smem;               // NW words <= 64KB
        for (int w = t; w < NW; w += BINB) hist[w] = 0;
        __syncthreads();
        const int hb   = (int)blockIdx.x - NT - GN;
        const int SEG  = (E + NH - 1) / NH;
        const int hbeg = hb * SEG;
        int hend = hbeg + SEG; if (hend > E) hend = E;
        for (int i = hbeg + t; i < hend; i += BINB) {
            unsigned c = (unsigned)cols[i];
            atomicAdd(&hist[c >> 2], 1u << ((c & 3u) * 8u));
        }
        __syncthreads();
        unsigned* dst = phist + (size_t)hb * NW;
        for (int w = t; w < NW; w += BINB) dst[w] = hist[w];
        return;
    }

    if ((int)blockIdx.x >= NT) {
        // ---------------- gemm path: 64x128 tile, waves 0-3 compute ------
        unsigned short (*wt)[136] = (unsigned short (*)[136])smem;            // 34816 B
        unsigned short (*xs)[136] = (unsigned short (*)[136])(smem + 34816);  // 17408 B
        const int row0 = ((int)blockIdx.x - NT) * 64;
        #pragma unroll
        for (int i = 0; i < 2; ++i) {         // W^T: 2048 ushort8 chunks
            int j = i * 1024 + t;
            int n = j >> 4, k8 = j & 15;
            us8 v = *(const us8*)&wtb[j * 8];
            *(us8*)&wt[n][k8 * 8] = v;
        }
        #pragma unroll
        for (int i = 0; i < 2; ++i) {         // x: 2048 float4 -> ushort4
            int j = i * 1024 + t;
            int r = j >> 5, c4 = j & 31;
            int gr = row0 + r;
            us4 o = (us4){0, 0, 0, 0};
            if (gr < N) {
                float4 v = *(const float4*)&x[(size_t)gr * D + c4 * 4];
                o = (us4){f2bf(v.x), f2bf(v.y), f2bf(v.z), f2bf(v.w)};
            }
            *(us4*)&xs[r][c4 * 4] = o;
        }
        __syncthreads();
        if (t < 256) {
            const int w  = t >> 6, l = t & 63;
            const int m0 = w * 16;
            const int lm = l & 15, lq = l >> 4;
            f32x4 acc[8];
            #pragma unroll
            for (int nt = 0; nt < 8; ++nt) acc[nt] = (f32x4){0.f, 0.f, 0.f, 0.f};
            #pragma unroll
            for (int kk = 0; kk < 4; ++kk) {
                const int kof = kk * 32 + lq * 8;
                bf16x8 a = *(const bf16x8*)&xs[m0 + lm][kof];
                #pragma unroll
                for (int nt = 0; nt < 8; ++nt) {
                    bf16x8 bb = *(const bf16x8*)&wt[nt * 16 + lm][kof];
                    acc[nt] = __builtin_amdgcn_mfma_f32_16x16x32_bf16(a, bb, acc[nt], 0, 0, 0);
                }
            }
            #pragma unroll
            for (int nt = 0; nt < 8; ++nt) {
                const int col = nt * 16 + lm;
                const float bc = bia[col];
                #pragma unroll
                for (int r = 0; r < 4; ++r) {
                    int grow = row0 + m0 + lq * 4 + r;
                    if (grow < N) xlb[(size_t)grow * D + col] = f2bf(acc[nt][r] + bc);
                }
            }
        }
        return;
    }

    // ---------------- bin path: row-bucket LDS sort, coalesced writes ----
    unsigned* sorted = (unsigned*)smem;                 // 32768 B
    int* lcnt  = (int*)(smem + 32768);                  // 800 ints each
    int* lbase = lcnt + 800;
    int* excl  = lcnt + 1600;
    int* cur   = lcnt + 2400;                           // ends at 45568 B

    const int base = blockIdx.x * TILE;
    int m = E - base; if (m > TILE) m = TILE;

    unsigned p[TILE / BINB];
    #pragma unroll
    for (int it = 0; it < TILE / BINB; ++it) {
        int i = it * BINB + t;
        if (i < m) {
            unsigned r = (unsigned)rows[base + i];
            unsigned c = (unsigned)cols[base + i];
            p[it] = c | ((r & 63u) << 16) | ((r >> 6) << 22);
        }
    }
    if (t < 800) lcnt[t] = 0;
    __syncthreads();
    #pragma unroll
    for (int it = 0; it < TILE / BINB; ++it) {
        int i = it * BINB + t;
        if (i < m) atomicAdd(&lcnt[p[it] >> 22], 1);
    }
    __syncthreads();
    // wave 0: scan 782 buckets, 13 keys/lane; write excl AND cur
    if (t < 64) {
        int v[13], s = 0;
        #pragma unroll
        for (int u = 0; u < 13; ++u) {
            int k = t * 13 + u;
            v[u] = (k < NBK) ? lcnt[k] : 0;
            s += v[u];
        }
        int inc = s;
        #pragma unroll
        for (int off = 1; off < 64; off <<= 1) { int o = __shfl_up(inc, off); if (t >= off) inc += o; }
        int run = inc - s;
        #pragma unroll
        for (int u = 0; u < 13; ++u) {
            int k = t * 13 + u;
            if (k < NBK) { excl[k] = run; cur[k] = run; }
            run += v[u];
        }
    }
    if (t < NBK) {                               // reserve global regions
        int c0 = lcnt[t];
        lbase[t] = c0 ? atomicAdd(&bcur[t], c0) : 0;
    }
    __syncthreads();
    #pragma unroll
    for (int it = 0; it < TILE / BINB; ++it) {   // scatter into LDS (random: free)
        int i = it * BINB + t;
        if (i < m) {
            int pos = atomicAdd(&cur[p[it] >> 22], 1);
            sorted[pos] = p[it];
        }
    }
    __syncthreads();
    #pragma unroll
    for (int it = 0; it < TILE / BINB; ++it) {   // positional coalesced writes
        int i = it * BINB + t;
        if (i < m) {
            unsigned pp = sorted[i];
            int bk = pp >> 22;
            int g  = lbase[bk] + i - excl[bk];
            if (g < (bk + 1) * CAPB) ebuf[g] = pp & 0x3FFFFFu;  // col | rl<<16
        }
    }
}

// --- merge NH partial histograms -> dis = rsqrt(deg+1) -------------------
__global__ __launch_bounds__(256) void k_dismerge(const unsigned* __restrict__ phist,
                                                  float* __restrict__ dis,
                                                  int N, int NW) {
    int w = blockIdx.x * 256 + threadIdx.x;
    if (w >= NW) return;
    unsigned s0 = 0, s1 = 0, s2 = 0, s3 = 0;
    const unsigned* pw = phist + w;
    #pragma unroll 8
    for (int b = 0; b < NH; ++b) {
        unsigned u = pw[(size_t)b * NW];
        s0 += u & 255u;
        s1 += (u >> 8) & 255u;
        s2 += (u >> 16) & 255u;
        s3 += u >> 24;
    }
    int c0 = w * 4;
    float4 o = make_float4(rsqrtf((float)(s0 + 1)), rsqrtf((float)(s1 + 1)),
                           rsqrtf((float)(s2 + 1)), rsqrtf((float)(s3 + 1)));
    if (c0 + 3 < N) {
        *(float4*)&dis[c0] = o;
    } else {
        if (c0     < N) dis[c0]     = o.x;
        if (c0 + 1 < N) dis[c0 + 1] = o.y;
        if (c0 + 2 < N) dis[c0 + 2] = o.z;
        if (c0 + 3 < N) dis[c0 + 3] = o.w;
    }
}

// --- block-per-bucket: LDS counting sort by row-local, then R15/R16-style
//     ping-pong register gather. out = dis_i*(dis_i*xl_i + sum dis_c*xl_c).
__global__ __launch_bounds__(512) void k_sortred2(const int* __restrict__ bcur,
                                                  const unsigned* __restrict__ ebuf,
                                                  const float* __restrict__ dis,
                                                  const unsigned short* __restrict__ xlb,
                                                  float* __restrict__ out, int N) {
    __shared__ unsigned short sorted[CAPB];     // 8 KB
    __shared__ int cnt[RPB];
    __shared__ int excl[RPB];
    __shared__ int cur[RPB];
    const int t = threadIdx.x, b = blockIdx.x;
    const int ebase = b * CAPB;
    int m = bcur[b] - ebase;
    if (m > CAPB) m = CAPB;
    if (m < 0) m = 0;

    unsigned p[CAPB / 512];                     // 8 regs
    #pragma unroll
    for (int it = 0; it < CAPB / 512; ++it) {
        int i = it * 512 + t;
        p[it] = (i < m) ? ebuf[ebase + i] : 0xFFFFFFFFu;
    }
    if (t < RPB) cnt[t] = 0;
    __syncthreads();
    #pragma unroll
    for (int it = 0; it < CAPB / 512; ++it)
        if (p[it] != 0xFFFFFFFFu) atomicAdd(&cnt[(p[it] >> 16) & 63], 1);
    __syncthreads();
    if (t < 64) {                               // 64-key wave scan
        int v = cnt[t], inc = v;
        #pragma unroll
        for (int off = 1; off < 64; off <<= 1) { int o = __shfl_up(inc, off); if (t >= off) inc += o; }
        excl[t] = inc - v;
        cur[t]  = inc - v;
    }
    __syncthreads();
    #pragma unroll
    for (int it = 0; it < CAPB / 512; ++it)     // scatter (random LDS: free)
        if (p[it] != 0xFFFFFFFFu) {
            int pos = atomicAdd(&cur[(p[it] >> 16) & 63], 1);
            sorted[pos] = (unsigned short)(p[it] & 0xFFFFu);
        }
    __syncthreads();

    const int wv = t >> 6, lane = t & 63;
    const int half = lane >> 5, l32 = lane & 31;

#define FETCH(V, NN, J) do { \
    _Pragma("unroll") \
    for (int u = 0; u < 8; ++u) { \
        int idx = (J) + 2 * u + half; \
        int cc = __shfl(c, idx); \
        NN[u] = __shfl(n, idx); \
        V[u] = *(const us4*)&xlb[((size_t)cc << 7) + (l32 << 2)]; \
    } } while (0)
#define CONS(V, NN) do { \
    _Pragma("unroll") \
    for (int u = 0; u < 8; ++u) { \
        a0 = fmaf(NN[u], bf2f(V[u][0]), a0); \
        a1 = fmaf(NN[u], bf2f(V[u][1]), a1); \
        a2 = fmaf(NN[u], bf2f(V[u][2]), a2); \
        a3 = fmaf(NN[u], bf2f(V[u][3]), a3); \
    } } while (0)

    // gather: wave wv owns rows wv*8 .. wv*8+7
    for (int r8 = 0; r8 < 8; ++r8) {
        const int rl = wv * 8 + r8;
        const int grow = b * RPB + rl;
        if (grow >= N) break;
        const float di = dis[grow];
        const int beg = excl[rl], end = cur[rl];
        // self loop: di*xl_i (times di at the end); only half 0 contributes
        us4 sv = *(const us4*)&xlb[(size_t)grow * D + (l32 << 2)];
        float s = (half == 0) ? di : 0.0f;
        float a0 = s * bf2f(sv[0]), a1 = s * bf2f(sv[1]);
        float a2 = s * bf2f(sv[2]), a3 = s * bf2f(sv[3]);
        for (int bs = beg; bs < end; bs += 64) {
            int mm = end - bs; if (mm > 64) mm = 64;
            int   c = 0;
            float n = 0.0f;
            if (lane < mm) {
                c = sorted[bs + lane];
                n = dis[c];
            }
            us4 A[8], B[8];
            float na[8], nb[8];
            int j = 0;
            FETCH(A, na, 0);
            for (; j + 32 <= mm; j += 32) {
                FETCH(B, nb, j + 16);           // issue next before consuming A
                CONS(A, na);
                if (j + 32 < mm) FETCH(A, na, j + 32);
                CONS(B, nb);
            }
            int rem = mm - j;                   // 0 < rem < 32 => A fetched at j
            if (rem > 0) {
                if (rem > 16) { FETCH(B, nb, j + 16); CONS(A, na); CONS(B, nb); }
                else          { CONS(A, na); }
            }
        }
        a0 += __shfl_xor(a0, 32);
        a1 += __shfl_xor(a1, 32);
        a2 += __shfl_xor(a2, 32);
        a3 += __shfl_xor(a3, 32);
        if (half == 0) {
            *(float4*)&out[(size_t)grow * D + (l32 << 2)] =
                make_float4(di * a0, di * a1, di * a2, di * a3);
        }
    }
#undef FETCH
#undef CONS
}

// ======================= fallback (R1 atomic path) =======================
__global__ __launch_bounds__(256) void k_zero(int* __restrict__ p, int n) {
    int i = blockIdx.x * 256 + threadIdx.x;
    if (i < n) p[i] = 0;
}
__global__ __launch_bounds__(256) void k_deg(const int* __restrict__ cols,
                                             int* __restrict__ cntc, int E) {
    int e = blockIdx.x * 256 + threadIdx.x;
    if (e < E) atomicAdd(&cntc[cols[e]], 1);
}
__global__ __launch_bounds__(256) void k_dis(const int* __restrict__ cntc,
                                             float* __restrict__ dis, int N) {
    int i = blockIdx.x * 256 + threadIdx.x;
    if (i < N) dis[i] = rsqrtf((float)(cntc[i] + 1));
}
#define GEMM_R 8
__global__ __launch_bounds__(128) void k_gemmf(const float* __restrict__ x,
                                               const float* __restrict__ W,
                                               const float* __restrict__ b,
                                               float* __restrict__ xl, int N) {
    __shared__ float xs[GEMM_R][D];
    const int c  = threadIdx.x;
    const int r0 = blockIdx.x * GEMM_R;
    #pragma unroll
    for (int r = 0; r < GEMM_R; ++r) {
        int row = r0 + r;
        xs[r][c] = (row < N) ? x[row * D + c] : 0.0f;
    }
    __syncthreads();
    float acc[GEMM_R];
    const float bc = b[c];
    #pragma unroll
    for (int r = 0; r < GEMM_R; ++r) acc[r] = bc;
    for (int k = 0; k < D; k += 4) {
        const float w0 = W[(k + 0) * D + c];
        const float w1 = W[(k + 1) * D + c];
        const float w2 = W[(k + 2) * D + c];
        const float w3 = W[(k + 3) * D + c];
        #pragma unroll
        for (int r = 0; r < GEMM_R; ++r) {
            const float4 xv = *reinterpret_cast<const float4*>(&xs[r][k]);
            acc[r] = fmaf(xv.x, w0, acc[r]);
            acc[r] = fmaf(xv.y, w1, acc[r]);
            acc[r] = fmaf(xv.z, w2, acc[r]);
            acc[r] = fmaf(xv.w, w3, acc[r]);
        }
    }
    #pragma unroll
    for (int r = 0; r < GEMM_R; ++r) {
        int row = r0 + r;
        if (row < N) xl[row * D + c] = acc[r];
    }
}
__global__ __launch_bounds__(256) void k_self(const float* __restrict__ xl,
                                              const float* __restrict__ dis,
                                              float* __restrict__ out, int N) {
    int gid = blockIdx.x * 256 + threadIdx.x;
    int i = gid >> 7;
    if (i < N) {
        float d = dis[i];
        out[gid] = d * d * xl[gid];
    }
}
__global__ __launch_bounds__(256) void k_scatter(const int* __restrict__ rows,
                                                 const int* __restrict__ cols,
                                                 const float* __restrict__ dis,
                                                 const float* __restrict__ xl,
                                                 float* __restrict__ out, int E) {
    long long gid = (long long)blockIdx.x * 256 + threadIdx.x;
    int e    = (int)(gid >> 6);
    int lane = (int)(gid & 63);
    if (e >= E) return;
    const int row = rows[e];
    const int col = cols[e];
    const float nrm = dis[row] * dis[col];
    atomicAdd(&out[row * D + lane],      nrm * xl[col * D + lane]);
    atomicAdd(&out[row * D + 64 + lane], nrm * xl[col * D + 64 + lane]);
}

// ======================= launch ==========================================
extern "C" void kernel_launch(void* const* d_in, const int* in_sizes, int n_in,
                              void* d_out, int out_size, void* d_ws, size_t ws_size,
                              hipStream_t stream) {
    const float* x   = (const float*)d_in[0];
    const int*   ei  = (const int*)d_in[1];
    const float* W   = (const float*)d_in[2];
    const float* b   = (const float*)d_in[3];
    float*       out = (float*)d_out;

    const int N = in_sizes[0] / D;   // 50000
    const int E = in_sizes[1] / 2;   // 1.6M
    const int* rows = ei;
    const int* cols = ei + E;
    const int NBK = (N + RPB - 1) / RPB;       // 782 buckets of 64 rows
    const int NT  = (E + TILE - 1) / TILE;     // 196 bin blocks
    const int GN  = (N + 63) / 64;             // 782 gemm blocks
    const int NW  = (N + 3) / 4;               // 12500 histogram words

    // ws layout
    char* p = (char*)d_ws;
    size_t off = 0;
    unsigned short* xlb     = (unsigned short*)(p + off); off += (size_t)N * D * 2;
    unsigned short* wtb     = (unsigned short*)(p + off); off += (size_t)D * D * 2;
    float*          dis     = (float*)(p + off);          off += (size_t)N * 4;
    int*            bcur    = (int*)(p + off);            off += (size_t)MAXBK * 4;
    unsigned*       ebuf    = (unsigned*)(p + off);       off += (size_t)NBK * CAPB * 4;
    unsigned*       phist   = (unsigned*)(p + off);       off += (size_t)NH * NW * 4;

    const int gN = (N + 255) / 256;
    const int gE = (E + 255) / 256;

    if (N <= 65536 && NBK <= MAXBK && ws_size >= off) {
        int gP = (D * D + 255) / 256;
        if (gP < (NBK + 255) / 256) gP = (NBK + 255) / 256;
        k_prep     <<<gP, 256, 0, stream>>>(W, wtb, bcur, NBK);
        k_binjoint3<<<NT + GN + NH, BINB, 0, stream>>>(rows, cols, bcur, ebuf,
                                                       x, wtb, b, xlb, phist,
                                                       E, N, NBK, NT, GN, NW);
        k_dismerge <<<(NW + 255) / 256, 256, 0, stream>>>(phist, dis, N, NW);
        k_sortred2 <<<NBK, 512, 0, stream>>>(bcur, ebuf, dis, xlb, out, N);
    } else {
        // fallback: R1 atomic scatter path (fp32 xl)
        char* q = (char*)d_ws;
        float* xl   = (float*)q;
        float* disF = (float*)(q + (size_t)N * D * 4);
        int*   cc   = (int*)(q + (size_t)N * D * 4 + (size_t)N * 4);
        k_zero <<<gN, 256, 0, stream>>>(cc, N);
        k_deg  <<<gE, 256, 0, stream>>>(cols, cc, E);
        k_dis  <<<gN, 256, 0, stream>>>(cc, disF, N);
        k_gemmf<<<(N + GEMM_R - 1) / GEMM_R, 128, 0, stream>>>(x, W, b, xl, N);
        k_self <<<((N * D) + 255) / 256, 256, 0, stream>>>(xl, disF, out, N);
        long long st = (long long)E * 64;
        k_scatter<<<(int)((st + 255) / 256), 256, 0, stream>>>(rows, cols, disF, xl, out, E);
    }
}